// Round 2
// baseline (621.072 us; speedup 1.0000x reference)
//
#include <hip/hip_runtime.h>
#include <math.h>

#define HW    4096
#define DKC   256
#define DVC   516

// ---------------------------------------------------------------------------
// Kernel A: q[b][d][px] = sum_c fc[b][c][px] * Qw[c][d]
// grid 512 = b(4) x dt(2) x pt(64); block 256 = pxq(16 lanes x 4px) x dg(16 x 8d)
// LDS-free: fc float4 loads are 64-lane 256B coalesced (dg groups broadcast);
// Qw rows are 256KB L2-resident broadcast reads. Pure-VALU bound (~14us floor).
// ---------------------------------------------------------------------------
__global__ __launch_bounds__(256) void k_proj(const float* __restrict__ fc,
                                              const float* __restrict__ Qw,
                                              float* __restrict__ q) {
    const int t   = threadIdx.x;
    const int pxq = t & 15;
    const int dg  = t >> 4;
    const int bid = blockIdx.x;
    const int b   = bid & 3;
    const int dt  = (bid >> 2) & 1;
    const int pt  = bid >> 3;                 // 0..63
    const int pxo = pt * 64 + pxq * 4;        // float4-aligned pixel offset
    const int d0  = dt * 128 + dg * 8;        // 8 d per thread

    float acc[8][4];
    #pragma unroll
    for (int i = 0; i < 8; ++i)
        #pragma unroll
        for (int j = 0; j < 4; ++j) acc[i][j] = 0.0f;

    const float* fcb = fc + (size_t)b * DKC * HW + pxo;
    #pragma unroll 2
    for (int c = 0; c < 256; ++c) {
        float4 f4 = *(const float4*)&fcb[c * HW];
        float4 w0 = *(const float4*)&Qw[c * DKC + d0];
        float4 w1 = *(const float4*)&Qw[c * DKC + d0 + 4];
        float wv[8] = {w0.x, w0.y, w0.z, w0.w, w1.x, w1.y, w1.z, w1.w};
        float fv[4] = {f4.x, f4.y, f4.z, f4.w};
        #pragma unroll
        for (int i = 0; i < 8; ++i)
            #pragma unroll
            for (int j = 0; j < 4; ++j)
                acc[i][j] += wv[i] * fv[j];
    }
    #pragma unroll
    for (int i = 0; i < 8; ++i) {
        float4 o = make_float4(acc[i][0], acc[i][1], acc[i][2], acc[i][3]);
        *(float4*)&q[(size_t)(b * DKC + d0 + i) * HW + pxo] = o;
    }
}

// ---------------------------------------------------------------------------
// Kernel B: scores + softmax -> attn[b][m][px] (f32 in ws)
// grid 256 (16-px tiles), 512 threads = m(32) x px(16).
// kbuf loads: lanes = 16 consecutive px = one aligned 64B segment per m in the
// wave (4 m/wave -> 4x64B per instr), each element read exactly once (134MB).
// q loads: all lanes in a row share (b,d) -> single 64B broadcast, L1/L2-hit.
// ---------------------------------------------------------------------------
__global__ __launch_bounds__(512) void k_scores(const float* __restrict__ q,
                                                const float* __restrict__ kbuf,
                                                float* __restrict__ attn,
                                                float temp) {
    __shared__ float sc[4 * 32 * 16];   // [b][m][px] scores
    const int t   = threadIdx.x;
    const int px  = t & 15;
    const int m   = t >> 4;             // 0..31
    const int px0 = blockIdx.x * 16;

    float acc[4] = {0.f, 0.f, 0.f, 0.f};
    const float* kp = kbuf + (size_t)m * DKC * HW + px0 + px;
    const float* qp = q + px0 + px;

    #pragma unroll 2
    for (int d = 0; d < 256; d += 4) {
        float kv[4];
        #pragma unroll
        for (int j = 0; j < 4; ++j) kv[j] = kp[(size_t)(d + j) * HW];
        #pragma unroll
        for (int b = 0; b < 4; ++b) {
            #pragma unroll
            for (int j = 0; j < 4; ++j) {
                float qv = qp[(size_t)(b * DKC + d + j) * HW];
                acc[b] += qv * kv[j];
            }
        }
    }
    #pragma unroll
    for (int b = 0; b < 4; ++b) sc[(b * 32 + m) * 16 + px] = acc[b] * temp;
    __syncthreads();

    if (t < 64) {
        const int b = t >> 4, p = t & 15;
        float mx = -1e30f;
        for (int mm = 0; mm < 32; ++mm) mx = fmaxf(mx, sc[(b * 32 + mm) * 16 + p]);
        float sum = 0.f;
        for (int mm = 0; mm < 32; ++mm) {
            float e = expf(sc[(b * 32 + mm) * 16 + p] - mx);
            sc[(b * 32 + mm) * 16 + p] = e;
            sum += e;
        }
        float inv = 1.0f / sum;
        for (int mm = 0; mm < 32; ++mm)
            attn[(size_t)(b * 32 + mm) * HW + px0 + p] = sc[(b * 32 + mm) * 16 + p] * inv;
    }
}

// ---------------------------------------------------------------------------
// Kernel C: out[b,c,px] = fm + 0.5 * sum_m attn[b,m,px] * vbuf[m,c,px]
// grid 1088 = 64 px-tiles (64 px) x 17 c-tiles (32 c); block 256 = pxq(16x4px)
// x cg(16 x 2c). All global streams float4, 256B-per-16-lane coalesced.
// attn tile [4][32][64] = 32KB LDS -> 5 blocks/CU.
// ---------------------------------------------------------------------------
__global__ __launch_bounds__(256) void k_out(const float* __restrict__ vbuf,
                                             const float* __restrict__ fm,
                                             const float* __restrict__ attn,
                                             float* __restrict__ out) {
    __shared__ float a_lds[4 * 32 * 64];     // [b][m][px]
    const int t   = threadIdx.x;
    const int px0 = (blockIdx.x & 63) * 64;
    const int ct  = blockIdx.x >> 6;         // 0..16

    #pragma unroll
    for (int i = 0; i < 8; ++i) {
        int f4  = i * 256 + t;               // 2048 float4 total
        int row = f4 >> 4;                   // (b*32+m)
        int col = f4 & 15;
        *(float4*)&a_lds[row * 64 + col * 4] =
            *(const float4*)&attn[(size_t)row * HW + px0 + col * 4];
    }
    __syncthreads();

    const int pxq = t & 15;
    const int cg  = t >> 4;
    const int c0  = ct * 32 + cg * 2;
    const int c1  = c0 + 1;
    const bool w0 = c0 < DVC, w1 = c1 < DVC;
    const int c0e = w0 ? c0 : DVC - 1;
    const int c1e = w1 ? c1 : DVC - 1;
    const int pxo = px0 + pxq * 4;

    float4 acc0[4], acc1[4];
    #pragma unroll
    for (int b = 0; b < 4; ++b) {
        acc0[b] = make_float4(0.f, 0.f, 0.f, 0.f);
        acc1[b] = make_float4(0.f, 0.f, 0.f, 0.f);
    }

    #pragma unroll 2
    for (int m = 0; m < 32; ++m) {
        float4 v0 = *(const float4*)&vbuf[(size_t)(m * DVC + c0e) * HW + pxo];
        float4 v1 = *(const float4*)&vbuf[(size_t)(m * DVC + c1e) * HW + pxo];
        #pragma unroll
        for (int b = 0; b < 4; ++b) {
            float4 a = *(const float4*)&a_lds[(b * 32 + m) * 64 + pxq * 4];
            acc0[b].x += a.x * v0.x; acc0[b].y += a.y * v0.y;
            acc0[b].z += a.z * v0.z; acc0[b].w += a.w * v0.w;
            acc1[b].x += a.x * v1.x; acc1[b].y += a.y * v1.y;
            acc1[b].z += a.z * v1.z; acc1[b].w += a.w * v1.w;
        }
    }

    #pragma unroll
    for (int b = 0; b < 4; ++b) {
        if (w0) {
            size_t idx = (size_t)(b * DVC + c0) * HW + pxo;
            float4 f = *(const float4*)&fm[idx];
            float4 o = make_float4(f.x + 0.5f * acc0[b].x, f.y + 0.5f * acc0[b].y,
                                   f.z + 0.5f * acc0[b].z, f.w + 0.5f * acc0[b].w);
            *(float4*)&out[idx] = o;
        }
        if (w1) {
            size_t idx = (size_t)(b * DVC + c1) * HW + pxo;
            float4 f = *(const float4*)&fm[idx];
            float4 o = make_float4(f.x + 0.5f * acc1[b].x, f.y + 0.5f * acc1[b].y,
                                   f.z + 0.5f * acc1[b].z, f.w + 0.5f * acc1[b].w);
            *(float4*)&out[idx] = o;
        }
    }
}

extern "C" void kernel_launch(void* const* d_in, const int* in_sizes, int n_in,
                              void* d_out, int out_size, void* d_ws, size_t ws_size,
                              hipStream_t stream) {
    const float* fc = (const float*)d_in[0];
    const float* fm = (const float*)d_in[1];
    const float* kb = (const float*)d_in[2];
    const float* vb = (const float*)d_in[3];
    const float* Qw = (const float*)d_in[4];
    // d_in[5] (K) and d_in[6] (V) are dead: cat(new,buffer)[-32:] == buffer.
    float* out  = (float*)d_out;
    float* attn = (float*)d_ws;                      // 4*32*4096 f32 = 2 MB
    float* qws  = (float*)d_ws + 4 * 32 * HW;        // 4*256*4096 f32 = 16.8 MB

    const float temp = (float)(log(32.0 * 4096.0 + 4096.0) / log(2.0) / 16.0);

    k_proj  <<<512,      256, 0, stream>>>(fc, Qw, qws);
    k_scores<<<256,      512, 0, stream>>>(qws, kb, attn, temp);
    k_out   <<<17 * 64,  256, 0, stream>>>(vb, fm, attn, out);
}